// Round 1
// baseline (847.967 us; speedup 1.0000x reference)
//
#include <hip/hip_runtime.h>

#define NN 50000
#define NE 800000
#define H 128
#define K3H 384

typedef __bf16 bf16x8 __attribute__((ext_vector_type(8)));
typedef float f32x4 __attribute__((ext_vector_type(4)));

__device__ inline unsigned short f2bf(float f) {
    unsigned int u = __float_as_uint(f);
    u += 0x7FFFu + ((u >> 16) & 1u);   // round-to-nearest-even
    return (unsigned short)(u >> 16);
}

__global__ void zero_aggr(float4* aggr) {
    int i = blockIdx.x * blockDim.x + threadIdx.x;
    aggr[i] = make_float4(0.f, 0.f, 0.f, 0.f);
}

// W1 [384][128] fp32 -> W1t [128][384] bf16 (transposed so B-tiles stage as rows)
__global__ void w1_transpose(const float* __restrict__ W1, unsigned short* __restrict__ W1t) {
    int o = blockIdx.x * 256 + threadIdx.x;
    if (o < K3H * H) {
        int n = o / K3H;
        int k = o - n * K3H;
        W1t[o] = f2bf(W1[k * H + n]);
    }
}

// Per 128-edge tile: msg = relu(cat(x[s],x[r],ef) @ W1 + b1); atomicAdd into aggr[recv]
__global__ __launch_bounds__(256) void edge_gemm(
        const float* __restrict__ x,
        const int* __restrict__ senders,
        const int* __restrict__ receivers,
        const float* __restrict__ edge_feat,
        const unsigned short* __restrict__ W1t,
        const float* __restrict__ b1,
        float* __restrict__ aggr) {
    // padded LDS: 72-short rows => row stride 144B; 16B frag reads land 2-way (free)
    __shared__ short lds_a[128 * 72];
    __shared__ short lds_b[128 * 72];
    __shared__ int s_send[128];
    __shared__ int s_recv[128];

    const int tid = threadIdx.x;
    const int e0 = blockIdx.x * 128;

    if (tid < 128) s_send[tid] = senders[e0 + tid];
    else           s_recv[tid - 128] = receivers[e0 + tid - 128];
    __syncthreads();

    const int lane = tid & 63;
    const int wave = tid >> 6;
    const int wm = wave >> 1, wn = wave & 1;
    const int q = lane >> 4, l15 = lane & 15;

    f32x4 acc[4][4];
#pragma unroll
    for (int i = 0; i < 4; i++)
#pragma unroll
        for (int j = 0; j < 4; j++) acc[i][j] = (f32x4){0.f, 0.f, 0.f, 0.f};

    const int a_seg  = tid & 15;  // 16 threads/row, 4 floats each = 64 cols
    const int a_row0 = tid >> 4;  // 16 rows/pass, 8 passes
    const int b_seg  = tid & 7;   // 8 threads/row, 8 bf16 each = 64 cols
    const int b_row0 = tid >> 3;  // 32 rows/pass, 4 passes

    for (int c = 0; c < 6; ++c) {
        const int coloff = (c & 1) * 64;
        // --- stage A (gather + fp32->bf16) ---
#pragma unroll
        for (int p = 0; p < 8; ++p) {
            int row = a_row0 + p * 16;
            const float* src;
            if (c < 2)      src = x + (size_t)s_send[row] * H + coloff;
            else if (c < 4) src = x + (size_t)s_recv[row] * H + coloff;
            else            src = edge_feat + (size_t)(e0 + row) * H + coloff;
            float4 v = *(const float4*)(src + a_seg * 4);
            uint2 pk;
            pk.x = (unsigned)f2bf(v.x) | ((unsigned)f2bf(v.y) << 16);
            pk.y = (unsigned)f2bf(v.z) | ((unsigned)f2bf(v.w) << 16);
            *(uint2*)&lds_a[row * 72 + a_seg * 4] = pk;
        }
        // --- stage B (already bf16, transposed: lds_b[n][k]) ---
#pragma unroll
        for (int p = 0; p < 4; ++p) {
            int n = b_row0 + p * 32;
            uint4 v = *(const uint4*)(W1t + n * K3H + c * 64 + b_seg * 8);
            *(uint4*)&lds_b[n * 72 + b_seg * 8] = v;
        }
        __syncthreads();

        const short* pa = lds_a + (wm * 64 + l15) * 72 + q * 8;
        const short* pb = lds_b + (wn * 64 + l15) * 72 + q * 8;
#pragma unroll
        for (int ks = 0; ks < 2; ++ks) {
            bf16x8 af[4], bfr[4];
#pragma unroll
            for (int mi = 0; mi < 4; mi++)
                af[mi] = *(const bf16x8*)(const void*)(pa + mi * 16 * 72 + ks * 32);
#pragma unroll
            for (int ni = 0; ni < 4; ni++)
                bfr[ni] = *(const bf16x8*)(const void*)(pb + ni * 16 * 72 + ks * 32);
#pragma unroll
            for (int mi = 0; mi < 4; mi++)
#pragma unroll
                for (int ni = 0; ni < 4; ni++)
                    acc[mi][ni] = __builtin_amdgcn_mfma_f32_16x16x32_bf16(
                        af[mi], bfr[ni], acc[mi][ni], 0, 0, 0);
        }
        __syncthreads();
    }

    // --- epilogue: bias + relu + atomic scatter-add ---
    float bias[4];
#pragma unroll
    for (int ni = 0; ni < 4; ni++) bias[ni] = b1[wn * 64 + ni * 16 + l15];

#pragma unroll
    for (int mi = 0; mi < 4; mi++) {
        int rbase = wm * 64 + mi * 16 + q * 4;   // C/D layout: row = quad*4 + reg
#pragma unroll
        for (int r = 0; r < 4; r++) {
            int rl = rbase + r;
            int recv = s_recv[rl];
            float* dst = aggr + (size_t)recv * H + wn * 64 + l15;
#pragma unroll
            for (int ni = 0; ni < 4; ni++) {
                float v = acc[mi][ni][r] + bias[ni];
                if (v > 0.f) atomicAdd(dst + ni * 16, v);  // relu: zeros contribute nothing
            }
        }
    }
}

// h = aggr + x; out = layernorm(h)*gamma + beta. One wave per node row.
__global__ void residual_ln(const float* __restrict__ aggr, const float* __restrict__ x,
                            const float* __restrict__ gamma, const float* __restrict__ beta,
                            float* __restrict__ out) {
    int node = blockIdx.x * 4 + (threadIdx.x >> 6);
    int lane = threadIdx.x & 63;
    size_t off = (size_t)node * H + lane * 2;
    float2 a  = *(const float2*)(aggr + off);
    float2 xv = *(const float2*)(x + off);
    float h0 = a.x + xv.x, h1 = a.y + xv.y;
    float s = h0 + h1, sq = h0 * h0 + h1 * h1;
#pragma unroll
    for (int o = 32; o > 0; o >>= 1) {
        s  += __shfl_xor(s, o);
        sq += __shfl_xor(sq, o);
    }
    float mu  = s * (1.f / 128.f);
    float var = sq * (1.f / 128.f) - mu * mu;
    float rstd = rsqrtf(var + 1e-5f);
    float2 o2;
    o2.x = gamma[lane * 2]     * (h0 - mu) * rstd + beta[lane * 2];
    o2.y = gamma[lane * 2 + 1] * (h1 - mu) * rstd + beta[lane * 2 + 1];
    *(float2*)(out + off) = o2;
}

extern "C" void kernel_launch(void* const* d_in, const int* in_sizes, int n_in,
                              void* d_out, int out_size, void* d_ws, size_t ws_size,
                              hipStream_t stream) {
    const float* x         = (const float*)d_in[0];
    const int*   senders   = (const int*)d_in[1];
    const int*   receivers = (const int*)d_in[2];
    const float* edge_feat = (const float*)d_in[3];
    const float* W1        = (const float*)d_in[4];
    const float* b1        = (const float*)d_in[5];
    const float* gamma     = (const float*)d_in[6];
    const float* beta      = (const float*)d_in[7];
    float* out  = (float*)d_out;
    float* aggr = (float*)d_ws;                                     // [NN][H] fp32
    unsigned short* W1t = (unsigned short*)((char*)d_ws + (size_t)NN * H * 4);  // [H][3H] bf16

    zero_aggr<<<NN * H / 4 / 256, 256, 0, stream>>>((float4*)aggr);
    w1_transpose<<<(K3H * H + 255) / 256, 256, 0, stream>>>(W1, W1t);
    edge_gemm<<<NE / 128, 256, 0, stream>>>(x, senders, receivers, edge_feat, W1t, b1, aggr);
    residual_ln<<<NN / 4, 256, 0, stream>>>(aggr, x, gamma, beta, out);
}